// Round 8
// baseline (42.729 us; speedup 1.0000x reference)
//
#include <hip/hip_runtime.h>
#include <math.h>

#define BATCH 32
#define NSAMP 262144
#define NKNOT 256
#define EPSV  0.001f
#define CH    16                  // samples per chunk (per thread)
#define CPB   256                 // chunks per block (= threads/block)
#define SPB   (CH * CPB)          // 4096 samples per block
#define NCROW (NSAMP / CH)        // 16384 chunks per row
#define BPR   (NCROW / CPB)       // 64 blocks per row (one wave scans it)
#define NB    (BATCH * BPR)       // 2048 blocks
#define NWAVE (CPB / 64)          // 4 waves per block
#define ROWW  20                  // padded words/row: 80B, 16B-aligned, 2x/bank max

// ---------------------------------------------------------------------------
// Kernel 1: per-block aggregate affine map, G stored transposed [6][NB]
// ---------------------------------------------------------------------------
__global__ __launch_bounds__(256, 4) void k_agg(
    const float* __restrict__ x,
    const float* __restrict__ cl,     // [BATCH][NKNOT][5]
    float* __restrict__ G)            // [6][NB]
{
    __shared__ float tile[CPB * ROWW];   // 20 KB
    __shared__ float wag[NWAVE][6];
    const int tid = threadIdx.x;
    const int b = blockIdx.x;
    const int lane = tid & 63, wid = tid >> 6;

    // coalesced global load -> LDS, one b128 per float4 (row-major [chunk][20])
    const float4* x4 = (const float4*)x + (size_t)b * (SPB / 4);
    #pragma unroll
    for (int i = 0; i < 4; ++i) {
        int ii = tid + i * CPB;
        float4 v = x4[ii];
        *(float4*)&tile[(ii >> 2) * ROWW + ((ii & 3) << 2)] = v;
    }

    // knot coefficients (channels 0,1)
    int chunk = b * CPB + tid;
    int r = chunk >> 14;                 // / NCROW
    int c = chunk & (NCROW - 1);
    const float scale = 255.0f / 262143.0f;
    float pos0 = (float)(c * CH) * scale;
    float fiA = floorf(pos0);
    int idxA = (int)fiA;
    float w0v = pos0 - fiA;
    const float* kb = cl + (size_t)r * NKNOT * 5;
    int i1 = min(idxA + 1, NKNOT - 1);
    int i2 = min(idxA + 2, NKNOT - 1);
    float k00 = kb[idxA*5+0], k01 = kb[i1*5+0], k02 = kb[i2*5+0];
    float k10 = kb[idxA*5+1], k11 = kb[i1*5+1], k12 = kb[i2*5+1];

    // first segment-B sample (16 if none); identical fmaf as per-sample test
    int jb = 0;
    #pragma unroll
    for (int j = 0; j < CH; ++j) jb += (fmaf((float)j, scale, w0v) < 1.0f) ? 1 : 0;

    // incremental-exp precompute: e_j = exp(2*l_j) advances by constant factor
    float dA0 = k01 - k00, dB0 = k02 - k01;
    float dA1 = k11 - k10, dB1 = k12 - k11;
    float wb  = fmaf((float)jb, scale, w0v) - 1.0f;
    float eA0 = __expf(2.0f * fmaf(w0v, dA0, k00));
    float EA0 = __expf(2.0f * scale * dA0);
    float eB0 = __expf(2.0f * fmaf(wb,  dB0, k01));
    float EB0 = __expf(2.0f * scale * dB0);
    float eA1 = __expf(2.0f * fmaf(w0v, dA1, k10));
    float EA1 = __expf(2.0f * scale * dA1);
    float eB1 = __expf(2.0f * fmaf(wb,  dB1, k11));
    float EB1 = __expf(2.0f * scale * dB1);

    __syncthreads();

    // build per-chunk affine map  s_end = M s_start + v
    const float stab = 1.0f - EPSV, stab2 = 2.0f * stab;
    float p1 = 0.f, p2 = 0.f, A1 = 1.f, A2 = 0.f, B1 = 0.f, B2 = 1.f;
    float e0 = eA0, e1 = eA1;
    #pragma unroll
    for (int jj = 0; jj < CH / 4; ++jj) {
        float4 xq = *(const float4*)&tile[tid * ROWW + (jj << 2)];
        #pragma unroll
        for (int q = 0; q < 4; ++q) {
            const int j = jj * 4 + q;
            if (j > 0) {
                float m0 = (j <= jb) ? EA0 : EB0;
                float m1 = (j <= jb) ? EA1 : EB1;
                e0 = (j == jb) ? eB0 : e0 * m0;
                e1 = (j == jb) ? eB1 : e1 * m1;
            }
            float r0 = __builtin_amdgcn_rcpf(e0 + 1.0f);
            float r1 = __builtin_amdgcn_rcpf(e1 + 1.0f);
            float th0 = fmaf(-2.0f, r0, 1.0f);          // tanh(l0)
            float th1 = fmaf(-2.0f, r1, 1.0f);          // tanh(l1)
            float a1 = stab2 * th0;
            float a1a = fabsf(a1);
            float a2 = 0.5f * fmaf((2.0f - a1a) * stab, th1, a1a);
            float xs = (&xq.x)[q];
            float p  = fmaf(-a2, p2, xs);  p = fmaf(-a1, p1, p);
            float hA = fmaf(-a1, A1, -a2 * A2);
            float hB = fmaf(-a1, B1, -a2 * B2);
            p2 = p1; p1 = p;
            A2 = A1; A1 = hA;
            B2 = B1; B1 = hB;
        }
    }
    float L00 = A1, L01 = B1, L10 = A2, L11 = B2, Lv0 = p1, Lv1 = p2;

    // wave-inclusive scan (compose later ∘ earlier)
    #pragma unroll
    for (int d = 1; d < 64; d <<= 1) {
        float o00 = __shfl_up(L00, d), o01 = __shfl_up(L01, d);
        float o10 = __shfl_up(L10, d), o11 = __shfl_up(L11, d);
        float ov0 = __shfl_up(Lv0, d), ov1 = __shfl_up(Lv1, d);
        if (lane >= d) {
            float n00 = L00 * o00 + L01 * o10;
            float n01 = L00 * o01 + L01 * o11;
            float n10 = L10 * o00 + L11 * o10;
            float n11 = L10 * o01 + L11 * o11;
            float nv0 = fmaf(L00, ov0, fmaf(L01, ov1, Lv0));
            float nv1 = fmaf(L10, ov0, fmaf(L11, ov1, Lv1));
            L00 = n00; L01 = n01; L10 = n10; L11 = n11; Lv0 = nv0; Lv1 = nv1;
        }
    }
    if (lane == 63) {
        wag[wid][0] = L00; wag[wid][1] = L01; wag[wid][2] = L10;
        wag[wid][3] = L11; wag[wid][4] = Lv0; wag[wid][5] = Lv1;
    }
    __syncthreads();

    if (tid == CPB - 1) {
        float P00 = 1.f, P01 = 0.f, P10 = 0.f, P11 = 1.f, Pv0 = 0.f, Pv1 = 0.f;
        for (int w2 = 0; w2 < NWAVE - 1; ++w2) {
            float a00 = wag[w2][0], a01 = wag[w2][1], a10 = wag[w2][2];
            float a11 = wag[w2][3], av0 = wag[w2][4], av1 = wag[w2][5];
            float n00 = a00 * P00 + a01 * P10;
            float n01 = a00 * P01 + a01 * P11;
            float n10 = a10 * P00 + a11 * P10;
            float n11 = a10 * P01 + a11 * P11;
            float nv0 = fmaf(a00, Pv0, fmaf(a01, Pv1, av0));
            float nv1 = fmaf(a10, Pv0, fmaf(a11, Pv1, av1));
            P00 = n00; P01 = n01; P10 = n10; P11 = n11; Pv0 = nv0; Pv1 = nv1;
        }
        G[0*NB + b] = L00 * P00 + L01 * P10;
        G[1*NB + b] = L00 * P01 + L01 * P11;
        G[2*NB + b] = L10 * P00 + L11 * P10;
        G[3*NB + b] = L10 * P01 + L11 * P11;
        G[4*NB + b] = fmaf(L00, Pv0, fmaf(L01, Pv1, Lv0));
        G[5*NB + b] = fmaf(L10, Pv0, fmaf(L11, Pv1, Lv1));
    }
}

// ---------------------------------------------------------------------------
// Kernel 2: inline row-scan of G + rebuild + intra-block scan + apply + FIR
// ---------------------------------------------------------------------------
__global__ __launch_bounds__(256, 4) void k_apply(
    const float* __restrict__ x,
    const float* __restrict__ cl,
    const float* __restrict__ G,      // [6][NB]
    float* __restrict__ out)
{
    __shared__ float tile[CPB * ROWW];
    __shared__ float wag[NWAVE][6];
    __shared__ float sInit[2];
    const int tid = threadIdx.x;
    const int b = blockIdx.x;
    const int lane = tid & 63, wid = tid >> 6;

    const float4* x4 = (const float4*)x + (size_t)b * (SPB / 4);
    #pragma unroll
    for (int i = 0; i < 4; ++i) {
        int ii = tid + i * CPB;
        float4 v = x4[ii];
        *(float4*)&tile[(ii >> 2) * ROWW + ((ii & 3) << 2)] = v;
    }

    // wave 0: scan this row's 64 block aggregates -> block-start state
    if (wid == 0) {
        int rowFirst = b & ~(BPR - 1);
        int k = rowFirst + lane;
        float A00 = G[0*NB + k], A01 = G[1*NB + k], A10 = G[2*NB + k];
        float A11 = G[3*NB + k], Av0 = G[4*NB + k], Av1 = G[5*NB + k];
        #pragma unroll
        for (int d = 1; d < 64; d <<= 1) {
            float o00 = __shfl_up(A00, d), o01 = __shfl_up(A01, d);
            float o10 = __shfl_up(A10, d), o11 = __shfl_up(A11, d);
            float ov0 = __shfl_up(Av0, d), ov1 = __shfl_up(Av1, d);
            if (lane >= d) {
                float n00 = A00 * o00 + A01 * o10;
                float n01 = A00 * o01 + A01 * o11;
                float n10 = A10 * o00 + A11 * o10;
                float n11 = A10 * o01 + A11 * o11;
                float nv0 = fmaf(A00, ov0, fmaf(A01, ov1, Av0));
                float nv1 = fmaf(A10, ov0, fmaf(A11, ov1, Av1));
                A00 = n00; A01 = n01; A10 = n10; A11 = n11; Av0 = nv0; Av1 = nv1;
            }
        }
        int myIdx = b & (BPR - 1);
        int src = (myIdx > 0) ? myIdx - 1 : 0;
        float s0 = __shfl(Av0, src);
        float s1 = __shfl(Av1, src);
        if (lane == 0) {
            sInit[0] = myIdx ? s0 : 0.f;
            sInit[1] = myIdx ? s1 : 0.f;
        }
    }

    // knot coefficients (all 5 channels)
    int chunk = b * CPB + tid;
    int r = chunk >> 14;
    int c = chunk & (NCROW - 1);
    const float scale = 255.0f / 262143.0f;
    float pos0 = (float)(c * CH) * scale;
    float fiA = floorf(pos0);
    int idxA = (int)fiA;
    float w0v = pos0 - fiA;
    const float* kb = cl + (size_t)r * NKNOT * 5;
    int i1 = min(idxA + 1, NKNOT - 1);
    int i2 = min(idxA + 2, NKNOT - 1);
    float k00 = kb[idxA*5+0], k01 = kb[i1*5+0], k02 = kb[i2*5+0];
    float k10 = kb[idxA*5+1], k11 = kb[i1*5+1], k12 = kb[i2*5+1];
    float k20 = kb[idxA*5+2], k21 = kb[i1*5+2], k22 = kb[i2*5+2];
    float k30 = kb[idxA*5+3], k31 = kb[i1*5+3], k32 = kb[i2*5+3];
    float k40 = kb[idxA*5+4], k41 = kb[i1*5+4], k42 = kb[i2*5+4];

    int jb = 0;
    #pragma unroll
    for (int j = 0; j < CH; ++j) jb += (fmaf((float)j, scale, w0v) < 1.0f) ? 1 : 0;

    float dA0 = k01 - k00, dB0 = k02 - k01;
    float dA1 = k11 - k10, dB1 = k12 - k11;
    float wb  = fmaf((float)jb, scale, w0v) - 1.0f;
    float eA0 = __expf(2.0f * fmaf(w0v, dA0, k00));
    float EA0 = __expf(2.0f * scale * dA0);
    float eB0 = __expf(2.0f * fmaf(wb,  dB0, k01));
    float EB0 = __expf(2.0f * scale * dB0);
    float eA1 = __expf(2.0f * fmaf(w0v, dA1, k10));
    float EA1 = __expf(2.0f * scale * dA1);
    float eB1 = __expf(2.0f * fmaf(wb,  dB1, k11));
    float EB1 = __expf(2.0f * scale * dB1);

    __syncthreads();

    // rebuild per-chunk affine map (a-channels only)
    const float stab = 1.0f - EPSV, stab2 = 2.0f * stab;
    float p1 = 0.f, p2 = 0.f, A1 = 1.f, A2 = 0.f, B1 = 0.f, B2 = 1.f;
    float e0 = eA0, e1 = eA1;
    #pragma unroll
    for (int jj = 0; jj < CH / 4; ++jj) {
        float4 xq = *(const float4*)&tile[tid * ROWW + (jj << 2)];
        #pragma unroll
        for (int q = 0; q < 4; ++q) {
            const int j = jj * 4 + q;
            if (j > 0) {
                float m0 = (j <= jb) ? EA0 : EB0;
                float m1 = (j <= jb) ? EA1 : EB1;
                e0 = (j == jb) ? eB0 : e0 * m0;
                e1 = (j == jb) ? eB1 : e1 * m1;
            }
            float r0 = __builtin_amdgcn_rcpf(e0 + 1.0f);
            float r1 = __builtin_amdgcn_rcpf(e1 + 1.0f);
            float th0 = fmaf(-2.0f, r0, 1.0f);
            float th1 = fmaf(-2.0f, r1, 1.0f);
            float a1 = stab2 * th0;
            float a1a = fabsf(a1);
            float a2 = 0.5f * fmaf((2.0f - a1a) * stab, th1, a1a);
            float xs = (&xq.x)[q];
            float p  = fmaf(-a2, p2, xs);  p = fmaf(-a1, p1, p);
            float hA = fmaf(-a1, A1, -a2 * A2);
            float hB = fmaf(-a1, B1, -a2 * B2);
            p2 = p1; p1 = p;
            A2 = A1; A1 = hA;
            B2 = B1; B1 = hB;
        }
    }
    float L00 = A1, L01 = B1, L10 = A2, L11 = B2, Lv0 = p1, Lv1 = p2;

    // wave-inclusive scan
    #pragma unroll
    for (int d = 1; d < 64; d <<= 1) {
        float o00 = __shfl_up(L00, d), o01 = __shfl_up(L01, d);
        float o10 = __shfl_up(L10, d), o11 = __shfl_up(L11, d);
        float ov0 = __shfl_up(Lv0, d), ov1 = __shfl_up(Lv1, d);
        if (lane >= d) {
            float n00 = L00 * o00 + L01 * o10;
            float n01 = L00 * o01 + L01 * o11;
            float n10 = L10 * o00 + L11 * o10;
            float n11 = L10 * o01 + L11 * o11;
            float nv0 = fmaf(L00, ov0, fmaf(L01, ov1, Lv0));
            float nv1 = fmaf(L10, ov0, fmaf(L11, ov1, Lv1));
            L00 = n00; L01 = n01; L10 = n10; L11 = n11; Lv0 = nv0; Lv1 = nv1;
        }
    }
    if (lane == 63) {
        wag[wid][0] = L00; wag[wid][1] = L01; wag[wid][2] = L10;
        wag[wid][3] = L11; wag[wid][4] = Lv0; wag[wid][5] = Lv1;
    }
    __syncthreads();
    float P00 = 1.f, P01 = 0.f, P10 = 0.f, P11 = 1.f, Pv0 = 0.f, Pv1 = 0.f;
    for (int w2 = 0; w2 < wid; ++w2) {
        float a00 = wag[w2][0], a01 = wag[w2][1], a10 = wag[w2][2];
        float a11 = wag[w2][3], av0 = wag[w2][4], av1 = wag[w2][5];
        float n00 = a00 * P00 + a01 * P10;
        float n01 = a00 * P01 + a01 * P11;
        float n10 = a10 * P00 + a11 * P10;
        float n11 = a10 * P01 + a11 * P11;
        float nv0 = fmaf(a00, Pv0, fmaf(a01, Pv1, av0));
        float nv1 = fmaf(a10, Pv0, fmaf(a11, Pv1, av1));
        P00 = n00; P01 = n01; P10 = n10; P11 = n11; Pv0 = nv0; Pv1 = nv1;
    }
    float E00 = __shfl_up(L00, 1), E01 = __shfl_up(L01, 1);
    float E10 = __shfl_up(L10, 1), E11 = __shfl_up(L11, 1);
    float Ev0 = __shfl_up(Lv0, 1), Ev1 = __shfl_up(Lv1, 1);
    if (lane == 0) { E00 = 1.f; E01 = 0.f; E10 = 0.f; E11 = 1.f; Ev0 = 0.f; Ev1 = 0.f; }
    float C00 = E00 * P00 + E01 * P10;
    float C01 = E00 * P01 + E01 * P11;
    float C10 = E10 * P00 + E11 * P10;
    float C11 = E10 * P01 + E11 * P11;
    float Cv0 = fmaf(E00, Pv0, fmaf(E01, Pv1, Ev0));
    float Cv1 = fmaf(E10, Pv0, fmaf(E11, Pv1, Ev1));

    float s0 = sInit[0], s1 = sInit[1];
    float y1 = fmaf(C00, s0, fmaf(C01, s1, Cv0));
    float y2 = fmaf(C10, s0, fmaf(C11, s1, Cv1));

    // apply recurrence + fused FIR, write back into tile
    e0 = eA0; e1 = eA1;
    #pragma unroll
    for (int jj = 0; jj < CH / 4; ++jj) {
        float* tp = &tile[tid * ROWW + (jj << 2)];
        float4 xq = *(const float4*)tp;
        float4 ov;
        #pragma unroll
        for (int q = 0; q < 4; ++q) {
            const int j = jj * 4 + q;
            if (j > 0) {
                float m0 = (j <= jb) ? EA0 : EB0;
                float m1 = (j <= jb) ? EA1 : EB1;
                e0 = (j == jb) ? eB0 : e0 * m0;
                e1 = (j == jb) ? eB1 : e1 * m1;
            }
            float r0 = __builtin_amdgcn_rcpf(e0 + 1.0f);
            float r1 = __builtin_amdgcn_rcpf(e1 + 1.0f);
            float th0 = fmaf(-2.0f, r0, 1.0f);
            float th1 = fmaf(-2.0f, r1, 1.0f);
            float a1 = stab2 * th0;
            float a1a = fabsf(a1);
            float a2 = 0.5f * fmaf((2.0f - a1a) * stab, th1, a1a);
            // b-channels: lerp with segment select (consistent with jb)
            float w = fmaf((float)j, scale, w0v);
            bool isB = (j >= jb);
            float wu = isB ? w - 1.0f : w;
            float b0 = fmaf(wu, isB ? (k22-k21) : (k21-k20), isB ? k21 : k20);
            float b1c = fmaf(wu, isB ? (k32-k31) : (k31-k30), isB ? k31 : k30);
            float b2c = fmaf(wu, isB ? (k42-k41) : (k41-k40), isB ? k41 : k40);
            float xs = (&xq.x)[q];
            float y = fmaf(-a2, y2, xs);  y = fmaf(-a1, y1, y);
            (&ov.x)[q] = fmaf(b0, y, fmaf(b1c, y1, b2c * y2));
            y2 = y1; y1 = y;
        }
        *(float4*)tp = ov;
    }
    __syncthreads();

    // coalesced float4 store
    float4* out4 = (float4*)out + (size_t)b * (SPB / 4);
    #pragma unroll
    for (int i = 0; i < 4; ++i) {
        int ii = tid + i * CPB;
        out4[ii] = *(const float4*)&tile[(ii >> 2) * ROWW + ((ii & 3) << 2)];
    }
}

extern "C" void kernel_launch(void* const* d_in, const int* in_sizes, int n_in,
                              void* d_out, int out_size, void* d_ws, size_t ws_size,
                              hipStream_t stream) {
    const float* x  = (const float*)d_in[0];   // [32][262144]
    const float* cl = (const float*)d_in[1];   // [32][256][5]
    float* out = (float*)d_out;
    float* G = (float*)d_ws;                   // [6][NB] floats (48 KB)

    hipLaunchKernelGGL(k_agg,   dim3(NB), dim3(CPB), 0, stream, x, cl, G);
    hipLaunchKernelGGL(k_apply, dim3(NB), dim3(CPB), 0, stream, x, cl, G, out);
}